// Round 12
// baseline (197.290 us; speedup 1.0000x reference)
//
#include <hip/hip_runtime.h>
#include <stdint.h>
#include <math.h>

typedef __attribute__((ext_vector_type(8))) short short8;   // 8 bf16 (4 VGPRs)
typedef __attribute__((ext_vector_type(4))) float f32x4;    // 4 fp32 acc

typedef __attribute__((address_space(1))) const uint32_t g_u32;
typedef __attribute__((address_space(3))) uint32_t l_u32;

static __device__ __forceinline__ uint16_t f2bf(float f) {
  union { float f; uint32_t u; } v; v.f = f;
  uint32_t r = (v.u + 0x7FFFu + ((v.u >> 16) & 1u)) >> 16;  // RNE
  return (uint16_t)r;
}

static __device__ __forceinline__ float bf2f(uint16_t u) {
  union { uint32_t u; float f; } v; v.u = ((uint32_t)u) << 16;
  return v.f;
}

static __device__ __forceinline__ uint32_t cvt_pk_bf16(float lo, float hi) {
  uint32_t r;
  asm("v_cvt_pk_bf16_f32 %0, %1, %2" : "=v"(r) : "v"(lo), "v"(hi));  // lo->low16
  return r;
}

static __device__ __forceinline__ float waveReduceSum(float x) {
#pragma unroll
  for (int m = 32; m > 0; m >>= 1) x += __shfl_xor(x, m, 64);
  return x;
}

// ---------------- zero the atomically-accumulated arrays
__global__ __launch_bounds__(256) void k_zero(float* __restrict__ p, int n4) {
  const int i = blockIdx.x * 256 + threadIdx.x;
  if (i < n4) reinterpret_cast<float4*>(p)[i] = float4{0.f, 0.f, 0.f, 0.f};
}

// ---------------- N pass: b_i = ||n_i||^2, sn_l = sum_i N[i][l], NtF =
// per-lane MFMA B-fragment stream (verified r10/r11):
// NtF[(gs*4 + w)*2048 + lane*32 + q*8] = N[gs*32 + (lane>>4)*8 + e][w*64 + q*16 + (lane&15)]
__global__ __launch_bounds__(256) void k_nt(const float* __restrict__ N,
                                            uint16_t* __restrict__ NtF,
                                            float* __restrict__ b,
                                            float* __restrict__ sn) {
  __shared__ __align__(16) uint16_t T[256 * 72];  // [l][k] k=0..63, pad 72
  const int i0 = blockIdx.x * 64;
  const int tid = threadIdx.x;
  const int wave = tid >> 6, lane = tid & 63;
  float sq[16];
  float snacc0 = 0.f, snacc1 = 0.f, snacc2 = 0.f, snacc3 = 0.f;
#pragma unroll
  for (int it = 0; it < 16; ++it) {
    const int k = wave + it * 4;
    const int l4 = lane * 4;
    const float4 v = *reinterpret_cast<const float4*>(N + (size_t)(i0 + k) * 256 + l4);
    T[(l4 + 0) * 72 + k] = f2bf(v.x);
    T[(l4 + 1) * 72 + k] = f2bf(v.y);
    T[(l4 + 2) * 72 + k] = f2bf(v.z);
    T[(l4 + 3) * 72 + k] = f2bf(v.w);
    sq[it] = v.x * v.x + v.y * v.y + v.z * v.z + v.w * v.w;
    snacc0 += v.x; snacc1 += v.y; snacc2 += v.z; snacc3 += v.w;
  }
#pragma unroll
  for (int m = 1; m < 64; m <<= 1) {
#pragma unroll
    for (int it = 0; it < 16; ++it) sq[it] += __shfl_xor(sq[it], m, 64);
  }
  float myv = sq[0];
#pragma unroll
  for (int it = 1; it < 16; ++it) myv = (lane == it) ? sq[it] : myv;
  if (lane < 16) b[i0 + wave + lane * 4] = myv;
  {
    const int l4 = lane * 4;
    atomicAdd(&sn[l4 + 0], snacc0); atomicAdd(&sn[l4 + 1], snacc1);
    atomicAdd(&sn[l4 + 2], snacc2); atomicAdd(&sn[l4 + 3], snacc3);
  }
  __syncthreads();
  const int lr = lane & 15, lh = lane >> 4;
#pragma unroll
  for (int tt = 0; tt < 2; ++tt) {
    const size_t base = ((size_t)(blockIdx.x * 2 + tt) * 4 + wave) * 2048 + (size_t)lane * 32;
#pragma unroll
    for (int q = 0; q < 4; ++q) {
      const int l = wave * 64 + q * 16 + lr;
      const short8 v = *reinterpret_cast<const short8*>(&T[l * 72 + tt * 32 + lh * 8]);
      *reinterpret_cast<short8*>(NtF + base + q * 8) = v;
    }
  }
}

// ---------------- h1_i = sum_l N[i][l] * sn[l]
__global__ __launch_bounds__(256) void k_h1(const float* __restrict__ N,
                                            const float* __restrict__ sn,
                                            float* __restrict__ h1) {
  const int wave = threadIdx.x >> 6, lane = threadIdx.x & 63;
  const int i = blockIdx.x * 4 + wave;
  const float4 v = *reinterpret_cast<const float4*>(N + (size_t)i * 256 + lane * 4);
  const float4 s = *reinterpret_cast<const float4*>(sn + lane * 4);
  float d = v.x * s.x + v.y * s.y + v.z * s.z + v.w * s.w;
  d = waveReduceSum(d);
  if (lane == 0) h1[i] = d;
}

// ---------------- X pass (only full X read). Tile 64i x 256p: each wave reads
// 1KB CONTIGUOUS per row (the coalescing fix). Computes ALL X stats in fp32,
// LDS-transposes ([p][i] u16, stride 66: frag read = one ds_read_b128), and
// emits XtF = per-lane MFMA A-fragment stream:
//   XtF[(pt*ngs + gs)*2048 + ps*512 + lane*8 + e]
//     = X_bf16[gs*32 + (lane>>4)*8 + e][pt*64 + ps*16 + (lane&15)]
__global__ __launch_bounds__(256) void k_xf(const float* __restrict__ X,
                                            const float* __restrict__ b,
                                            const float* __restrict__ h1v,
                                            uint16_t* __restrict__ XtF,
                                            float* __restrict__ sx,
                                            float* __restrict__ cx,
                                            float* __restrict__ scalA,
                                            int B, int D1) {
  __shared__ __align__(16) uint16_t T[256 * 66];   // [p_local][i], stride 66
  __shared__ float colS[256], colC[256];
  const int tid = threadIdx.x;
  const int w = tid >> 6, lane = tid & 63;
  const int nbx = D1 >> 8;             // col-blocks of 256
  const int bx = blockIdx.x % nbx;
  const int by = blockIdx.x / nbx;     // row-block of 64
  const int p0 = bx << 8, i0 = by << 6;
  const int ngs = B >> 5;

  colS[tid] = 0.f; colC[tid] = 0.f;

  const int col4 = lane << 2;
  float s1 = 0.f, sb = 0.f, sh = 0.f;
  float cs0 = 0.f, cs1 = 0.f, cs2 = 0.f, cs3 = 0.f;
  float cc0 = 0.f, cc1 = 0.f, cc2 = 0.f, cc3 = 0.f;
#pragma unroll
  for (int sw = 0; sw < 16; ++sw) {
    const int i = sw * 4 + w;           // wave reads ONE row per sweep: 1KB contig
    const float4 v = *reinterpret_cast<const float4*>(X + (size_t)(i0 + i) * D1 + p0 + col4);
    const float bi = b[i0 + i], hi = h1v[i0 + i];
    const float d = v.x * v.x + v.y * v.y + v.z * v.z + v.w * v.w;
    s1 += d; sb += bi * d; sh += hi * d;
    cs0 += v.x; cs1 += v.y; cs2 += v.z; cs3 += v.w;
    cc0 += bi * v.x; cc1 += bi * v.y; cc2 += bi * v.z; cc3 += bi * v.w;
    const uint32_t w01 = cvt_pk_bf16(v.x, v.y);
    const uint32_t w23 = cvt_pk_bf16(v.z, v.w);
    T[(col4 + 0) * 66 + i] = (uint16_t)(w01 & 0xffffu);
    T[(col4 + 1) * 66 + i] = (uint16_t)(w01 >> 16);
    T[(col4 + 2) * 66 + i] = (uint16_t)(w23 & 0xffffu);
    T[(col4 + 3) * 66 + i] = (uint16_t)(w23 >> 16);
  }
  __syncthreads();

  // fragment emission: wave w owns pt_local = w; 2 gs images x 4 ps frags
  const int lr = lane & 15, lh = lane >> 4;
#pragma unroll
  for (int gsl = 0; gsl < 2; ++gsl) {
    const size_t img = ((size_t)(bx * 4 + w) * ngs + (size_t)(by * 2 + gsl)) * 2048;
#pragma unroll
    for (int ps = 0; ps < 4; ++ps) {
      const int pl = w * 64 + ps * 16 + lr;
      const short8 v = *reinterpret_cast<const short8*>(&T[pl * 66 + gsl * 32 + lh * 8]);
      *reinterpret_cast<short8*>(XtF + img + ps * 512 + (size_t)lane * 8) = v;
    }
  }

  // stats: column sums via LDS atomics (4 contenders/slot), scalars via slots
  atomicAdd(&colS[col4 + 0], cs0); atomicAdd(&colS[col4 + 1], cs1);
  atomicAdd(&colS[col4 + 2], cs2); atomicAdd(&colS[col4 + 3], cs3);
  atomicAdd(&colC[col4 + 0], cc0); atomicAdd(&colC[col4 + 1], cc1);
  atomicAdd(&colC[col4 + 2], cc2); atomicAdd(&colC[col4 + 3], cc3);
  s1 = waveReduceSum(s1); sb = waveReduceSum(sb); sh = waveReduceSum(sh);
  if (lane == 0) {
    float* slotp = scalA + (size_t)(((blockIdx.x << 2) + w) & 63) * 4;
    atomicAdd(&slotp[0], s1);
    atomicAdd(&slotp[1], sb);
    atomicAdd(&slotp[2], sh);
  }
  __syncthreads();
  atomicAdd(&sx[p0 + tid], colS[tid]);
  atomicAdd(&cx[p0 + tid], colC[tid]);
}

// ---------------- barrier-free, LDS-free GEMM. Both operands are per-lane
// dwordx4 fragment streams (XtF from HBM/L2, NtF L2-resident). 1-step register
// double-buffer; waves fully independent; compiler emits counted vmcnt only.
__global__ __launch_bounds__(256) void k_gemm_f10(const uint16_t* __restrict__ XtF,
                                                  const uint16_t* __restrict__ NtF,
                                                  uint16_t* __restrict__ Mb,
                                                  int B, int D1) {
  const int tid = threadIdx.x;
  const int w = tid >> 6, lane = tid & 63;
  const int lr = lane & 15, lh = lane >> 4;
  const int nks = B >> 7;                 // 32 ksteps per chunk
  const int ngs = B >> 5;
  const int pt = blockIdx.x >> 2, kc = blockIdx.x & 3;
  const int pbase = pt << 6;
  const int ks0 = kc * nks;

  f32x4 acc[4][4];
#pragma unroll
  for (int i = 0; i < 4; ++i)
#pragma unroll
    for (int j = 0; j < 4; ++j) acc[i][j] = (f32x4){0.f, 0.f, 0.f, 0.f};

  const uint16_t* xb = XtF + ((size_t)pt * ngs + ks0) * 2048 + (size_t)lane * 8;
  const uint16_t* nb = NtF + ((size_t)(ks0 * 4 + w)) * 2048 + (size_t)lane * 32;

  short8 afA[4], bfA[4], afB[4], bfB[4];

#define LOADF(AF, BF, S)                                                    \
  {                                                                         \
    const uint16_t* xp_ = xb + (size_t)(S) * 2048;                          \
    _Pragma("unroll")                                                       \
    for (int ps = 0; ps < 4; ++ps)                                          \
      AF[ps] = *reinterpret_cast<const short8*>(xp_ + ps * 512);            \
    const uint16_t* np_ = nb + (size_t)(S) * 8192;                          \
    _Pragma("unroll")                                                       \
    for (int q = 0; q < 4; ++q)                                             \
      BF[q] = *reinterpret_cast<const short8*>(np_ + q * 8);                \
  }
#define MM(AF, BF)                                                          \
  {                                                                         \
    _Pragma("unroll")                                                       \
    for (int ps = 0; ps < 4; ++ps)                                          \
      _Pragma("unroll")                                                     \
      for (int q = 0; q < 4; ++q)                                           \
        acc[ps][q] = __builtin_amdgcn_mfma_f32_16x16x32_bf16(AF[ps], BF[q], \
                                                             acc[ps][q], 0, 0, 0); \
  }

  LOADF(afA, bfA, 0);
  for (int s = 0; s < nks; s += 2) {
    const int s1c = (s + 1 < nks) ? s + 1 : nks - 1;
    const int s2c = (s + 2 < nks) ? s + 2 : nks - 1;
    LOADF(afB, bfB, s1c);
    MM(afA, bfA);
    LOADF(afA, bfA, s2c);   // tail: harmless reload, never accumulated twice
    MM(afB, bfB);
  }
#undef LOADF
#undef MM

  // M slice store [l][p] bf16; C/D layout col=lane&15 (l), row=(lane>>4)*4+e (p)
  uint16_t* Mk = Mb + (size_t)kc * ((size_t)D1 * 256);
#pragma unroll
  for (int ps = 0; ps < 4; ++ps)
#pragma unroll
    for (int q = 0; q < 4; ++q) {
      const int l = (w << 6) + (q << 4) + lr;
      const int p0e = pbase + ps * 16 + lh * 4;
      ushort4 st;
      st.x = f2bf(acc[ps][q][0]); st.y = f2bf(acc[ps][q][1]);
      st.z = f2bf(acc[ps][q][2]); st.w = f2bf(acc[ps][q][3]);
      *reinterpret_cast<ushort4*>(&Mk[(size_t)l * D1 + p0e]) = st;
    }
}

// ---------------- F = sum over elements of (sum_c m_c)^2, bf16 slices
__global__ __launch_bounds__(256) void k_square(const uint16_t* __restrict__ Mb,
                                                float* __restrict__ Fp,
                                                int n8, size_t slice, int nslice) {
  __shared__ float red[4];
  float s = 0.f;
  for (int idx = blockIdx.x * 256 + threadIdx.x; idx < n8; idx += gridDim.x * 256) {
    float v[8] = {0.f, 0.f, 0.f, 0.f, 0.f, 0.f, 0.f, 0.f};
    for (int c = 0; c < nslice; ++c) {
      union { short8 v8; uint16_t u[8]; } m;
      m.v8 = *reinterpret_cast<const short8*>(Mb + (size_t)idx * 8 + (size_t)c * slice);
#pragma unroll
      for (int e = 0; e < 8; ++e) v[e] += bf2f(m.u[e]);
    }
#pragma unroll
    for (int e = 0; e < 8; ++e) s += v[e] * v[e];
  }
  s = waveReduceSum(s);
  const int wave = threadIdx.x >> 6, lane = threadIdx.x & 63;
  if (lane == 0) red[wave] = s;
  __syncthreads();
  if (threadIdx.x == 0) atomicAdd(Fp, red[0] + red[1] + red[2] + red[3]);
}

// ---------------- final combine (slot-array scalars)
__global__ __launch_bounds__(256) void k_final4(const float* __restrict__ scalA,
                                                const float* __restrict__ Fp,
                                                const float* __restrict__ b,
                                                const float* __restrict__ sx,
                                                const float* __restrict__ cx,
                                                float* __restrict__ out,
                                                int B, int D1) {
  const int tid = threadIdx.x;
  float sa_ = 0.f, sab_ = 0.f, t1_ = 0.f, sb_ = 0.f, t2_ = 0.f;
  if (tid < 64) {
    sa_ = scalA[tid * 4 + 0];
    sab_ = scalA[tid * 4 + 1];
    t1_ = scalA[tid * 4 + 2];
  }
  for (int i = tid; i < B; i += 256) sb_ += b[i];
  for (int k = tid; k < D1; k += 256) t2_ += sx[k] * cx[k];
  sa_ = waveReduceSum(sa_); sab_ = waveReduceSum(sab_); t1_ = waveReduceSum(t1_);
  sb_ = waveReduceSum(sb_); t2_ = waveReduceSum(t2_);
  __shared__ float R[5][4];
  const int wave = tid >> 6, lane = tid & 63;
  if (lane == 0) { R[0][wave] = sa_; R[1][wave] = sab_; R[2][wave] = t1_; R[3][wave] = sb_; R[4][wave] = t2_; }
  __syncthreads();
  if (tid == 0) {
    double Sa = 0, Sab = 0, T1 = 0, Sb = 0, T2 = 0;
    for (int w = 0; w < 4; ++w) {
      Sa += R[0][w]; Sab += R[1][w]; T1 += R[2][w]; Sb += R[3][w]; T2 += R[4][w];
    }
    const double F = (double)Fp[0];
    const double total = 2.0 * (double)B * Sab + 2.0 * Sa * Sb - 4.0 * T1 - 4.0 * T2 + 4.0 * F;
    const double denom = (double)D1 * 256.0 * (double)B * (double)B;
    out[0] = (float)exp(-total / denom);
  }
}

// ================= tier-2 fallback (round-3 verified path) =================
__global__ __launch_bounds__(256) void k_nt2(const float* __restrict__ N,
                                             uint16_t* __restrict__ Nt,
                                             float* __restrict__ b,
                                             float* __restrict__ sn) {
  __shared__ __align__(16) uint16_t T[256 * 72];
  const int i0 = blockIdx.x * 64;
  const int tid = threadIdx.x;
  const int wave = tid >> 6, lane = tid & 63;
  float sq[16];
  float snacc0 = 0.f, snacc1 = 0.f, snacc2 = 0.f, snacc3 = 0.f;
#pragma unroll
  for (int it = 0; it < 16; ++it) {
    const int k = wave + it * 4;
    const int l4 = lane * 4;
    const float4 v = *reinterpret_cast<const float4*>(N + (size_t)(i0 + k) * 256 + l4);
    T[(l4 + 0) * 72 + k] = f2bf(v.x);
    T[(l4 + 1) * 72 + k] = f2bf(v.y);
    T[(l4 + 2) * 72 + k] = f2bf(v.z);
    T[(l4 + 3) * 72 + k] = f2bf(v.w);
    sq[it] = v.x * v.x + v.y * v.y + v.z * v.z + v.w * v.w;
    snacc0 += v.x; snacc1 += v.y; snacc2 += v.z; snacc3 += v.w;
  }
#pragma unroll
  for (int m = 1; m < 64; m <<= 1) {
#pragma unroll
    for (int it = 0; it < 16; ++it) sq[it] += __shfl_xor(sq[it], m, 64);
  }
  float myv = sq[0];
#pragma unroll
  for (int it = 1; it < 16; ++it) myv = (lane == it) ? sq[it] : myv;
  if (lane < 16) b[i0 + wave + lane * 4] = myv;
  {
    const int l4 = lane * 4;
    atomicAdd(&sn[l4 + 0], snacc0); atomicAdd(&sn[l4 + 1], snacc1);
    atomicAdd(&sn[l4 + 2], snacc2); atomicAdd(&sn[l4 + 3], snacc3);
  }
  __syncthreads();
  const int l = tid;
#pragma unroll
  for (int tt = 0; tt < 2; ++tt) {
    const int tg = blockIdx.x * 2 + tt;
#pragma unroll
    for (int c = 0; c < 4; ++c) {
      const short8 v = *reinterpret_cast<const short8*>(&T[l * 72 + tt * 32 + c * 8]);
      *reinterpret_cast<short8*>((char*)Nt + (size_t)tg * 16384 + l * 64 +
                                 ((c ^ (l & 3)) << 4)) = v;
    }
  }
}

__global__ __launch_bounds__(256, 3) void k_gemm_f3(const float* __restrict__ X,
                                                    const uint16_t* __restrict__ Nt,
                                                    uint16_t* __restrict__ Mb,
                                                    const float* __restrict__ bvec,
                                                    const float* __restrict__ h1v,
                                                    float* __restrict__ sx,
                                                    float* __restrict__ cx,
                                                    float* __restrict__ scal,
                                                    int B, int D1) {
  __shared__ __align__(16) uint16_t NB[2][8192];
  __shared__ __align__(16) uint16_t AB[2][64 * 40];
  __shared__ float SR[3][4];
  const int tid = threadIdx.x;
  const int w = tid >> 6, lane = tid & 63;
  const int lr = lane & 15, lh = lane >> 4;
  const int nks = B >> 7;
  const int pt = blockIdx.x >> 2, kc = blockIdx.x & 3;
  const int pbase = pt << 6;
  const int ks0 = kc * nks;

  f32x4 acc[4][4];
#pragma unroll
  for (int i = 0; i < 4; ++i)
#pragma unroll
    for (int j = 0; j < 4; ++j) acc[i][j] = (f32x4){0.f, 0.f, 0.f, 0.f};

  const int ap = tid & 63, ak8 = (tid >> 6) << 3;
  const float* Xbase = X + (size_t)(ks0 * 32 + ak8) * D1 + pbase + ap;
  float xr[8];
  float4 bv0, bv1, hv0, hv1;
  float s1 = 0.f, sb = 0.f, sh = 0.f, sxa = 0.f, cxa = 0.f;

#define GLL_B(S, BUF)                                                              \
  {                                                                                \
    const char* gsrc_ = (const char*)Nt + (size_t)(ks0 + (S)) * 16384 +            \
                        ((size_t)w << 10) + (size_t)lane * 16;                     \
    _Pragma("unroll")                                                              \
    for (int j_ = 0; j_ < 4; ++j_) {                                               \
      __builtin_amdgcn_global_load_lds((g_u32*)(gsrc_ + ((size_t)j_ << 12)),       \
                                       (l_u32*)&NB[BUF][(j_ * 4 + w) << 9],        \
                                       16, 0, 0);                                  \
    }                                                                              \
  }
#define A_LOADS(S)                                                                 \
  {                                                                                \
    const float* p_ = Xbase + (size_t)(S) * 32 * D1;                               \
    _Pragma("unroll")                                                              \
    for (int r_ = 0; r_ < 8; ++r_) xr[r_] = p_[(size_t)r_ * D1];                   \
    const int ib_ = ks0 * 32 + (S) * 32 + ak8;                                     \
    bv0 = *reinterpret_cast<const float4*>(bvec + ib_);                            \
    bv1 = *reinterpret_cast<const float4*>(bvec + ib_ + 4);                        \
    hv0 = *reinterpret_cast<const float4*>(h1v + ib_);                             \
    hv1 = *reinterpret_cast<const float4*>(h1v + ib_ + 4);                         \
  }

  GLL_B(0, 0);
  A_LOADS(0);

  for (int s = 0; s < nks; ++s) {
    const int buf = s & 1;
    {
      union { uint16_t u[8]; short8 v; } pk;
      const float bb[8] = {bv0.x, bv0.y, bv0.z, bv0.w, bv1.x, bv1.y, bv1.z, bv1.w};
      const float hh[8] = {hv0.x, hv0.y, hv0.z, hv0.w, hv1.x, hv1.y, hv1.z, hv1.w};
#pragma unroll
      for (int r = 0; r < 8; ++r) {
        const float x = xr[r];
        pk.u[r] = f2bf(x);
        const float x2 = x * x;
        s1 += x2; sb += bb[r] * x2; sh += hh[r] * x2;
        sxa += x; cxa += bb[r] * x;
      }
      *reinterpret_cast<short8*>(&AB[buf][ap * 40 + ak8]) = pk.v;
    }
    __syncthreads();
    if (s + 1 < nks) {
      GLL_B(s + 1, buf ^ 1);
      A_LOADS(s + 1);
    }
    short8 af[4], bfv[4];
#pragma unroll
    for (int ps = 0; ps < 4; ++ps)
      af[ps] = *reinterpret_cast<const short8*>(&AB[buf][(ps * 16 + lr) * 40 + lh * 8]);
#pragma unroll
    for (int q = 0; q < 4; ++q) {
      const int l = (w << 6) + (q << 4) + lr;
      bfv[q] = *reinterpret_cast<const short8*>(&NB[buf][l * 32 + ((lh ^ (l & 3)) << 3)]);
    }
#pragma unroll
    for (int ps = 0; ps < 4; ++ps)
#pragma unroll
      for (int q = 0; q < 4; ++q)
        acc[ps][q] = __builtin_amdgcn_mfma_f32_16x16x32_bf16(af[ps], bfv[q], acc[ps][q], 0, 0, 0);
    __syncthreads();
  }
#undef GLL_B
#undef A_LOADS

  uint16_t* Mk = Mb + (size_t)kc * ((size_t)D1 * 256);
#pragma unroll
  for (int ps = 0; ps < 4; ++ps)
#pragma unroll
    for (int q = 0; q < 4; ++q) {
      const int l = (w << 6) + (q << 4) + lr;
      const int p0 = pbase + ps * 16 + lh * 4;
      ushort4 st;
      st.x = f2bf(acc[ps][q][0]); st.y = f2bf(acc[ps][q][1]);
      st.z = f2bf(acc[ps][q][2]); st.w = f2bf(acc[ps][q][3]);
      *reinterpret_cast<ushort4*>(&Mk[(size_t)l * D1 + p0]) = st;
    }

  atomicAdd(&sx[pbase + ap], sxa);
  atomicAdd(&cx[pbase + ap], cxa);

  s1 = waveReduceSum(s1); sb = waveReduceSum(sb); sh = waveReduceSum(sh);
  if (lane == 0) { SR[0][w] = s1; SR[1][w] = sb; SR[2][w] = sh; }
  __syncthreads();
  if (tid == 0) {
    atomicAdd(&scal[0], SR[0][0] + SR[0][1] + SR[0][2] + SR[0][3]);
    atomicAdd(&scal[1], SR[1][0] + SR[1][1] + SR[1][2] + SR[1][3]);
    atomicAdd(&scal[2], SR[2][0] + SR[2][1] + SR[2][2] + SR[2][3]);
  }
}

__global__ __launch_bounds__(256) void k_final3(const float* __restrict__ scal,
                                                const float* __restrict__ b,
                                                const float* __restrict__ sx,
                                                const float* __restrict__ cx,
                                                float* __restrict__ out,
                                                int B, int D1) {
  const int tid = threadIdx.x;
  float sb_ = 0.f, t2_ = 0.f;
  for (int i = tid; i < B; i += 256) sb_ += b[i];
  for (int k = tid; k < D1; k += 256) t2_ += sx[k] * cx[k];
  sb_ = waveReduceSum(sb_); t2_ = waveReduceSum(t2_);
  __shared__ float R[2][4];
  const int wave = tid >> 6, lane = tid & 63;
  if (lane == 0) { R[0][wave] = sb_; R[1][wave] = t2_; }
  __syncthreads();
  if (tid == 0) {
    double Sb = 0, T2 = 0;
    for (int w = 0; w < 4; ++w) { Sb += R[0][w]; T2 += R[1][w]; }
    const double Sa = scal[0], Sab = scal[1], T1 = scal[2], F = scal[3];
    const double total = 2.0 * (double)B * Sab + 2.0 * Sa * Sb - 4.0 * T1 - 4.0 * T2 + 4.0 * F;
    const double denom = (double)D1 * 256.0 * (double)B * (double)B;
    out[0] = (float)exp(-total / denom);
  }
}

extern "C" void kernel_launch(void* const* d_in, const int* in_sizes, int n_in,
                              void* d_out, int out_size, void* d_ws, size_t ws_size,
                              hipStream_t stream) {
  const float* noises = (const float*)d_in[0];   // [B, 256]
  const float* images = (const float*)d_in[1];   // [B, D1]
  const int B = in_sizes[0] / 256;               // 4096
  const int D1 = in_sizes[1] / B;                // 12288
  float* outf = (float*)d_out;
  float* ws = (float*)d_ws;

  // ---- tier-1 layout (floats) ----
  float* sx    = ws;                        // D1   (atomic, zeroed)
  float* cx    = ws + D1;                   // D1   (atomic, zeroed)
  float* sn    = ws + 2 * D1;               // 256  (atomic, zeroed)
  float* scalA = ws + 2 * D1 + 256;         // 64*4 (atomic, zeroed)
  float* Fp    = ws + 2 * D1 + 512;         // 1    (atomic, zeroed; pad to 544)
  float* b     = ws + 2 * D1 + 544;         // B (fully written)
  float* h1    = b + B;                     // B (fully written)
  const size_t nt_off = ((size_t)2 * D1 + 544 + 2 * (size_t)B + 3) & ~(size_t)3;
  uint16_t* NtF = (uint16_t*)(ws + nt_off);                   // B*256 u16
  const size_t xtf_off = nt_off + ((size_t)B * 256) / 2;
  uint16_t* XtF = (uint16_t*)(ws + xtf_off);                  // B*D1 u16
  const size_t mb_off = xtf_off + ((size_t)B * D1) / 2;
  uint16_t* Mb = (uint16_t*)(ws + mb_off);                    // 4*D1*256 u16
  const size_t need1 = (mb_off + 2 * (size_t)D1 * 256) * sizeof(float);

  if (ws_size >= need1 && (B & 255) == 0 && (D1 & 255) == 0) {
    const int nzero4 = (2 * D1 + 544) / 4;
    k_zero<<<(nzero4 + 255) / 256, 256, 0, stream>>>(ws, nzero4);
    k_nt<<<B / 64, 256, 0, stream>>>(noises, NtF, b, sn);
    k_h1<<<B / 4, 256, 0, stream>>>(noises, sn, h1);
    k_xf<<<(B / 64) * (D1 / 256), 256, 0, stream>>>(images, b, h1, XtF, sx, cx, scalA, B, D1);
    k_gemm_f10<<<(D1 / 64) * 4, 256, 0, stream>>>(XtF, NtF, Mb, B, D1);
    k_square<<<512, 256, 0, stream>>>(Mb, Fp, D1 * 256 / 8, (size_t)D1 * 256, 4);
    k_final4<<<1, 256, 0, stream>>>(scalA, Fp, b, sx, cx, outf, B, D1);
  } else {
    // tier-2: round-3 verified path
    float* sx2   = ws;
    float* cx2   = ws + D1;
    float* sn2   = ws + 2 * D1;
    float* scal2 = ws + 2 * D1 + 256;        // {Sa, Sab, T1, F}
    float* b2    = ws + 2 * D1 + 272;
    float* h12   = b2 + B;
    const size_t nt2_off = ((size_t)2 * D1 + 272 + 2 * (size_t)B + 3) & ~(size_t)3;
    uint16_t* Nt2 = (uint16_t*)(ws + nt2_off);
    const size_t mb2_off = nt2_off + ((size_t)B * 256) / 2;
    uint16_t* Mb2 = (uint16_t*)(ws + mb2_off);
    const int nzero4 = (2 * D1 + 272) / 4;
    k_zero<<<(nzero4 + 255) / 256, 256, 0, stream>>>(ws, nzero4);
    k_nt2<<<B / 64, 256, 0, stream>>>(noises, Nt2, b2, sn2);
    k_h1<<<B / 4, 256, 0, stream>>>(noises, sn2, h12);
    k_gemm_f3<<<(D1 / 64) * 4, 256, 0, stream>>>(images, Nt2, Mb2, b2, h12, sx2, cx2, scal2, B, D1);
    k_square<<<512, 256, 0, stream>>>(Mb2, &scal2[3], D1 * 256 / 8, (size_t)D1 * 256, 4);
    k_final3<<<1, 256, 0, stream>>>(scal2, b2, sx2, cx2, outf, B, D1);
  }
}